// Round 25
// baseline (347.311 us; speedup 1.0000x reference)
//
#include <hip/hip_runtime.h>
#include <hip/hip_bf16.h>

// Problem constants (B=4, S=2048, D=1024, E=8, K=2, DFF=2048)
#define T_TOK 8192
#define D_DIM 1024
#define E_NUM 8
#define TOPK 2
#define DFF_DIM 2048
#define BM 128
#define BK 64
#define MAX_TILES 136                 // 17 * 8: per-XCD chunking is exactly bijective
#define MAX_PAIRS_PAD (MAX_TILES*BM)  // 17408

typedef __attribute__((ext_vector_type(8))) short short8_t;
typedef __attribute__((ext_vector_type(4))) float f32x4;

__device__ __forceinline__ unsigned short f2b(float f) {
  union { float f; unsigned u; } v; v.f = f;
  unsigned u = v.u;
  return (unsigned short)((u + 0x7fffu + ((u >> 16) & 1u)) >> 16);
}

// exact-GELU via A&S 7.1.26 erf (|err|<=1.5e-7, branchless ~15 VALU ops).
__device__ __forceinline__ float fast_gelu(float v) {
  float x = v * 0.70710678118654752f;
  float ax = fabsf(x);
  float t = __frcp_rn(1.f + 0.3275911f * ax);
  float poly = t * (0.254829592f + t * (-0.284496736f + t * (1.421413741f +
               t * (-1.453152027f + t * 1.061405429f))));
  float erfax = 1.f - poly * __expf(-x * x);
  float erfx = copysignf(erfax, x);
  return 0.5f * v * (1.f + erfx);
}

__device__ __forceinline__ void gload_lds16(const void* g, void* l) {
  __builtin_amdgcn_global_load_lds(
      (const __attribute__((address_space(1))) unsigned int*)g,
      (__attribute__((address_space(3))) unsigned int*)l, 16, 0, 0);
}

// ---- merged transpose+cvt: w1[1024][16384] and w2[16384][1024] -> bf16^T ----
__global__ void tcvt64_kernel(const float* __restrict__ w1, unsigned short* __restrict__ w1t,
                              const float* __restrict__ w2, unsigned short* __restrict__ w2t) {
  __shared__ float tile[64][68];
  int id = blockIdx.x;
  const float* src; unsigned short* dst; int R, C, bx, by;
  if (id < 4096) { src = w1; dst = w1t; R = 1024; C = 16384; bx = id & 255; by = id >> 8; }
  else { id -= 4096; src = w2; dst = w2t; R = 16384; C = 1024; bx = id & 15; by = id >> 4; }
  const int c0 = bx * 64, r0 = by * 64;
  const int t = threadIdx.x;
  #pragma unroll
  for (int i = 0; i < 4; ++i) {
    int idx = i * 256 + t;
    int row = idx >> 4, c4 = (idx & 15) * 4;
    float4 v = *(const float4*)&src[(size_t)(r0 + row) * C + c0 + c4];
    tile[row][c4] = v.x; tile[row][c4 + 1] = v.y;
    tile[row][c4 + 2] = v.z; tile[row][c4 + 3] = v.w;
  }
  __syncthreads();
  #pragma unroll
  for (int i = 0; i < 4; ++i) {
    int idx = i * 256 + t;
    int cOut = idx >> 4, r4 = (idx & 15) * 4;
    ushort4 o;
    o.x = f2b(tile[r4][cOut]);     o.y = f2b(tile[r4 + 1][cOut]);
    o.z = f2b(tile[r4 + 2][cOut]); o.w = f2b(tile[r4 + 3][cOut]);
    *(ushort4*)&dst[(size_t)(c0 + cOut) * R + r0 + r4] = o;
  }
}

// ---------------- router: logits, top-2, renorm; fused x->bf16; no hot atomics
__global__ void router_kernel(const float* __restrict__ x, const float* __restrict__ rw,
                              int* __restrict__ sel, float* __restrict__ selw,
                              unsigned short* __restrict__ xb) {
  int tok = (blockIdx.x * blockDim.x + threadIdx.x) >> 6;  // one wave per token
  int lane = threadIdx.x & 63;
  if (tok >= T_TOK) return;
  const float4* xr = (const float4*)(x + (size_t)tok * D_DIM);
  ushort4* xbr = (ushort4*)(xb + (size_t)tok * D_DIM);
  float acc[E_NUM];
  #pragma unroll
  for (int e = 0; e < E_NUM; ++e) acc[e] = 0.f;
  #pragma unroll
  for (int it = 0; it < 4; ++it) {
    int i = it * 64 + lane;      // float4 index, 0..255
    float4 v = xr[i];
    ushort4 o;
    o.x = f2b(v.x); o.y = f2b(v.y); o.z = f2b(v.z); o.w = f2b(v.w);
    xbr[i] = o;                  // fused bf16 conversion of x
    const float* w = rw + (size_t)i * 4 * E_NUM;
    #pragma unroll
    for (int e = 0; e < E_NUM; ++e) acc[e] += v.x * w[e];
    #pragma unroll
    for (int e = 0; e < E_NUM; ++e) acc[e] += v.y * w[E_NUM + e];
    #pragma unroll
    for (int e = 0; e < E_NUM; ++e) acc[e] += v.z * w[2 * E_NUM + e];
    #pragma unroll
    for (int e = 0; e < E_NUM; ++e) acc[e] += v.w * w[3 * E_NUM + e];
  }
  #pragma unroll
  for (int e = 0; e < E_NUM; ++e) {
    float v = acc[e];
    #pragma unroll
    for (int off = 32; off > 0; off >>= 1) v += __shfl_xor(v, off, 64);
    acc[e] = v;
  }
  if (lane == 0) {
    float mx = acc[0];
    #pragma unroll
    for (int e = 1; e < E_NUM; ++e) mx = fmaxf(mx, acc[e]);
    float p[E_NUM];
    #pragma unroll
    for (int e = 0; e < E_NUM; ++e) p[e] = __expf(acc[e] - mx);
    int i0 = 0;
    #pragma unroll
    for (int e = 1; e < E_NUM; ++e) if (p[e] > p[i0]) i0 = e;
    int i1 = (i0 == 0) ? 1 : 0;
    #pragma unroll
    for (int e = 0; e < E_NUM; ++e) if (e != i0 && p[e] > p[i1]) i1 = e;
    float w0 = p[i0], w1 = p[i1];
    float inv = 1.f / (w0 + w1);   // softmax denominator cancels in renorm
    sel[tok * 2] = i0; selw[tok * 2] = w0 * inv;
    sel[tok * 2 + 1] = i1; selw[tok * 2 + 1] = w1 * inv;
  }
}

// ---------------- counts: LDS-aggregated histogram ----------------
__global__ void count_kernel(const int* __restrict__ sel, int* __restrict__ counts) {
  __shared__ int lc[E_NUM];
  if (threadIdx.x < E_NUM) lc[threadIdx.x] = 0;
  __syncthreads();
  int t = blockIdx.x * blockDim.x + threadIdx.x;
  if (t < 2 * T_TOK) atomicAdd(&lc[sel[t]], 1);
  __syncthreads();
  if (threadIdx.x < E_NUM) atomicAdd(&counts[threadIdx.x], lc[threadIdx.x]);
}

// ---------------- plan: padded offsets + tile table + inits ----------------
__global__ void plan_kernel(const int* __restrict__ counts, int* __restrict__ tiles_e,
                            int* __restrict__ tiles_b, int* __restrict__ pad_off,
                            int* __restrict__ cursor, int* __restrict__ ptok,
                            float* __restrict__ pgate, unsigned short* __restrict__ zpad) {
  if (threadIdx.x == 0) {
    int b = 0, t = 0;
    for (int e = 0; e < E_NUM; ++e) {
      pad_off[e] = b;
      int nt = (counts[e] + BM - 1) >> 7;
      for (int i = 0; i < nt; ++i) { tiles_e[t] = e; tiles_b[t] = b + i * BM; ++t; }
      b += nt * BM;
    }
    for (; t < MAX_TILES; ++t) { tiles_e[t] = -1; tiles_b[t] = 0; }
  }
  for (int i = threadIdx.x; i < MAX_PAIRS_PAD; i += blockDim.x) { ptok[i] = -1; pgate[i] = 0.f; }
  for (int i = threadIdx.x; i < 64; i += blockDim.x) zpad[i] = 0;
  if (threadIdx.x < E_NUM) cursor[threadIdx.x] = 0;
}

// ---------------- scatter: block-level range reservation ----------------
__global__ void scatter_kernel(const int* __restrict__ sel, const float* __restrict__ selw,
                               const int* __restrict__ pad_off, int* __restrict__ cursor,
                               int* __restrict__ ptok, float* __restrict__ pgate) {
  __shared__ int lc[E_NUM];
  __shared__ int lbase[E_NUM];
  if (threadIdx.x < E_NUM) lc[threadIdx.x] = 0;
  __syncthreads();
  int t = blockIdx.x * blockDim.x + threadIdx.x;  // one thread per token
  int e0 = sel[t * 2], e1 = sel[t * 2 + 1];
  int o0 = atomicAdd(&lc[e0], 1);
  int o1 = atomicAdd(&lc[e1], 1);
  __syncthreads();
  if (threadIdx.x < E_NUM) lbase[threadIdx.x] = atomicAdd(&cursor[threadIdx.x], lc[threadIdx.x]);
  __syncthreads();
  int s0 = pad_off[e0] + lbase[e0] + o0;
  ptok[s0] = t; pgate[s0] = selw[t * 2];
  int s1 = pad_off[e1] + lbase[e1] + o1;
  ptok[s1] = t; pgate[s1] = selw[t * 2 + 1];
}

// ======== GEMM1: single-buffer BK=64 + T1 XCD chunking + T2 swizzle ========
__global__ __launch_bounds__(256, 3) void gemm1_kernel(
    const unsigned short* __restrict__ xb, const unsigned short* __restrict__ w1t,
    const int* __restrict__ ptok, const int* __restrict__ tiles_e,
    const int* __restrict__ tiles_b, const unsigned short* __restrict__ zpad,
    unsigned short* __restrict__ h) {
  const int id = blockIdx.x + 16 * blockIdx.y;
  const int xcd = id & 7;
  const int j = id >> 3;                     // 0..271 per XCD
  const int tileIdx = xcd * 17 + (j >> 4);   // 17 tiles per XCD
  const int n0 = (j & 15) * 128;
  const int e = tiles_e[tileIdx];
  if (e < 0) return;
  const int base = tiles_b[tileIdx];

  __shared__ unsigned short As[BM * BK];
  __shared__ unsigned short Bs[BM * BK];

  const int tid = threadIdx.x;
  const int lane = tid & 63;
  const int wv = tid >> 6;
  const int wr = wv >> 1, wc = wv & 1;
  const int lr = lane & 15;
  const int lq = lane >> 4;
  const int lsw = lr & 7;                     // read-side swizzle key

  int atok[4], aoff[4];
  const unsigned short* bptr[4];
  #pragma unroll
  for (int i = 0; i < 4; ++i) {
    int c = i * 256 + tid;
    int row = c >> 3, kc = c & 7;
    int kcs = kc ^ (row & 7);                 // inverse-swizzled source chunk
    atok[i] = ptok[base + row];
    aoff[i] = kcs * 8;
    bptr[i] = w1t + (size_t)(e * DFF_DIM + n0 + row) * D_DIM + kcs * 8;
  }

  f32x4 acc[4][4];
  #pragma unroll
  for (int m = 0; m < 4; ++m)
    #pragma unroll
    for (int n = 0; n < 4; ++n) acc[m][n] = (f32x4){0.f, 0.f, 0.f, 0.f};

  for (int k0 = 0; k0 < D_DIM; k0 += BK) {
    #pragma unroll
    for (int i = 0; i < 4; ++i) {
      const unsigned short* ga =
          (atok[i] >= 0) ? (xb + (size_t)atok[i] * D_DIM + k0 + aoff[i]) : zpad;
      gload_lds16(ga, &As[(i * 256 + tid) * 8]);          // LDS dest linear
      gload_lds16(bptr[i] + k0, &Bs[(i * 256 + tid) * 8]);
    }
    __syncthreads();
    #pragma unroll
    for (int kk = 0; kk < BK; kk += 32) {
      const int ch = (((kk >> 5) * 4 + lq) ^ lsw) * 8;    // swizzled read chunk
      short8_t aF[4], bF[4];
      #pragma unroll
      for (int m = 0; m < 4; ++m)
        aF[m] = *(const short8_t*)&As[(wr * 64 + m * 16 + lr) * BK + ch];
      #pragma unroll
      for (int n = 0; n < 4; ++n)
        bF[n] = *(const short8_t*)&Bs[(wc * 64 + n * 16 + lr) * BK + ch];
      #pragma unroll
      for (int m = 0; m < 4; ++m)
        #pragma unroll
        for (int n = 0; n < 4; ++n)
          acc[m][n] = __builtin_amdgcn_mfma_f32_16x16x32_bf16(aF[m], bF[n], acc[m][n], 0, 0, 0);
    }
    __syncthreads();
  }

  #pragma unroll
  for (int m = 0; m < 4; ++m) {
    #pragma unroll
    for (int n = 0; n < 4; ++n) {
      const int col = n0 + wc * 64 + n * 16 + lr;
      #pragma unroll
      for (int j4 = 0; j4 < 4; ++j4) {
        const int row = base + wr * 64 + m * 16 + lq * 4 + j4;
        h[(size_t)row * DFF_DIM + col] = f2b(fast_gelu(acc[m][n][j4]));
      }
    }
  }
}

// ======== GEMM2: split-K=2 (blockIdx.z), single-buffer + T1 + T2 ========
// out[tok] += gate * (h[:,khalf] @ W2_e[khalf,:]); halves merge via atomicAdd.
__global__ __launch_bounds__(256, 3) void gemm2_kernel(
    const unsigned short* __restrict__ h, const unsigned short* __restrict__ w2t,
    const int* __restrict__ ptok, const float* __restrict__ pgate,
    const int* __restrict__ tiles_e, const int* __restrict__ tiles_b,
    float* __restrict__ out) {
  const int id = blockIdx.x + 8 * blockIdx.y;
  const int xcd = id & 7;
  const int j = id >> 3;                     // 0..135 per XCD
  const int tileIdx = xcd * 17 + (j >> 3);   // 17 tiles per XCD
  const int n0 = (j & 7) * 128;
  const int kbase = blockIdx.z << 10;        // split-K: 0 or 1024
  const int e = tiles_e[tileIdx];
  if (e < 0) return;
  const int base = tiles_b[tileIdx];

  __shared__ unsigned short As[BM * BK];
  __shared__ unsigned short Bs[BM * BK];

  const int tid = threadIdx.x;
  const int lane = tid & 63;
  const int wv = tid >> 6;
  const int wr = wv >> 1, wc = wv & 1;
  const int lr = lane & 15;
  const int lq = lane >> 4;
  const int lsw = lr & 7;

  const unsigned short* aptr[4];
  const unsigned short* bptr[4];
  #pragma unroll
  for (int i = 0; i < 4; ++i) {
    int c = i * 256 + tid;
    int row = c >> 3, kc = c & 7;
    int kcs = kc ^ (row & 7);                 // inverse-swizzled source chunk
    aptr[i] = h + (size_t)(base + row) * DFF_DIM + kbase + kcs * 8;
    bptr[i] = w2t + (size_t)(n0 + row) * (E_NUM * DFF_DIM) + e * DFF_DIM + kbase + kcs * 8;
  }

  f32x4 acc[4][4];
  #pragma unroll
  for (int m = 0; m < 4; ++m)
    #pragma unroll
    for (int n = 0; n < 4; ++n) acc[m][n] = (f32x4){0.f, 0.f, 0.f, 0.f};

  for (int k0 = 0; k0 < DFF_DIM / 2; k0 += BK) {   // 16 K-steps per half
    #pragma unroll
    for (int i = 0; i < 4; ++i) {
      gload_lds16(aptr[i] + k0, &As[(i * 256 + tid) * 8]);
      gload_lds16(bptr[i] + k0, &Bs[(i * 256 + tid) * 8]);
    }
    __syncthreads();
    #pragma unroll
    for (int kk = 0; kk < BK; kk += 32) {
      const int ch = (((kk >> 5) * 4 + lq) ^ lsw) * 8;
      short8_t aF[4], bF[4];
      #pragma unroll
      for (int m = 0; m < 4; ++m)
        aF[m] = *(const short8_t*)&As[(wr * 64 + m * 16 + lr) * BK + ch];
      #pragma unroll
      for (int n = 0; n < 4; ++n)
        bF[n] = *(const short8_t*)&Bs[(wc * 64 + n * 16 + lr) * BK + ch];
      #pragma unroll
      for (int m = 0; m < 4; ++m)
        #pragma unroll
        for (int n = 0; n < 4; ++n)
          acc[m][n] = __builtin_amdgcn_mfma_f32_16x16x32_bf16(aF[m], bF[n], acc[m][n], 0, 0, 0);
    }
    __syncthreads();
  }

  #pragma unroll
  for (int m = 0; m < 4; ++m) {
    #pragma unroll
    for (int j4 = 0; j4 < 4; ++j4) {
      const int p = base + wr * 64 + m * 16 + lq * 4 + j4;
      const int tok = ptok[p];
      if (tok < 0) continue;
      const float g = pgate[p];
      #pragma unroll
      for (int n = 0; n < 4; ++n) {
        const int col = n0 + wc * 64 + n * 16 + lr;
        atomicAdd(&out[(size_t)tok * D_DIM + col], g * acc[m][n][j4]);
      }
    }
  }
}

// ---------------- launch ----------------
extern "C" void kernel_launch(void* const* d_in, const int* in_sizes, int n_in,
                              void* d_out, int out_size, void* d_ws, size_t ws_size,
                              hipStream_t stream) {
  const float* x  = (const float*)d_in[0];
  const float* rw = (const float*)d_in[1];
  const float* w1 = (const float*)d_in[2];
  const float* w2 = (const float*)d_in[3];
  float* out = (float*)d_out;

  char* ws = (char*)d_ws;
  unsigned short* xb   = (unsigned short*)(ws);              // 16,777,216
  unsigned short* w1t  = (unsigned short*)(ws + 16777216);   // 33,554,432  [16384][1024]
  unsigned short* w2t  = (unsigned short*)(ws + 50331648);   // 33,554,432  [1024][16384]
  unsigned short* h    = (unsigned short*)(ws + 83886080);   // 71,303,168  [17408][2048]
  int*   ptok   = (int*)(ws + 155189248);
  float* pgate  = (float*)(ws + 155258880);
  int*   sel    = (int*)(ws + 155328512);
  float* selw   = (float*)(ws + 155394048);
  int*   counts = (int*)(ws + 155459584);
  int*   cursor = counts + 8;
  int*   padoff = counts + 16;
  int*   tiles_e = counts + 24;
  int*   tiles_b = tiles_e + MAX_TILES;
  unsigned short* zpad = (unsigned short*)(tiles_b + MAX_TILES);
  const size_t WS_NEED = 155459584 + 4096;
  if (ws_size < WS_NEED) return;

  hipMemsetAsync(out, 0, (size_t)T_TOK * D_DIM * sizeof(float), stream);
  hipMemsetAsync(counts, 0, E_NUM * sizeof(int), stream);

  tcvt64_kernel<<<8192, 256, 0, stream>>>(w1, w1t, w2, w2t);
  router_kernel<<<T_TOK / 4, 256, 0, stream>>>(x, rw, sel, selw, xb);
  count_kernel<<<2 * T_TOK / 256, 256, 0, stream>>>(sel, counts);
  plan_kernel<<<1, 256, 0, stream>>>(counts, tiles_e, tiles_b, padoff, cursor, ptok, pgate, zpad);
  scatter_kernel<<<T_TOK / 256, 256, 0, stream>>>(sel, selw, padoff, cursor, ptok, pgate);
  gemm1_kernel<<<dim3(DFF_DIM / 128, MAX_TILES), 256, 0, stream>>>(xb, w1t, ptok, tiles_e,
                                                                   tiles_b, zpad, h);
  gemm2_kernel<<<dim3(D_DIM / 128, MAX_TILES, 2), 256, 0, stream>>>(h, w2t, ptok, pgate,
                                                                    tiles_e, tiles_b, out);
}

// Round 26
// 314.259 us; speedup vs baseline: 1.1052x; 1.1052x over previous
//
#include <hip/hip_runtime.h>
#include <hip/hip_bf16.h>

// Problem constants (B=4, S=2048, D=1024, E=8, K=2, DFF=2048)
#define T_TOK 8192
#define D_DIM 1024
#define E_NUM 8
#define TOPK 2
#define DFF_DIM 2048
#define BM 128
#define BK 64
#define MAX_TILES 136                 // 17 * 8: per-XCD chunking is exactly bijective
#define MAX_PAIRS_PAD (MAX_TILES*BM)  // 17408

typedef __attribute__((ext_vector_type(8))) short short8_t;
typedef __attribute__((ext_vector_type(4))) float f32x4;

__device__ __forceinline__ unsigned short f2b(float f) {
  union { float f; unsigned u; } v; v.f = f;
  unsigned u = v.u;
  return (unsigned short)((u + 0x7fffu + ((u >> 16) & 1u)) >> 16);
}

// exact-GELU via A&S 7.1.26 erf (|err|<=1.5e-7, branchless ~15 VALU ops).
__device__ __forceinline__ float fast_gelu(float v) {
  float x = v * 0.70710678118654752f;
  float ax = fabsf(x);
  float t = __frcp_rn(1.f + 0.3275911f * ax);
  float poly = t * (0.254829592f + t * (-0.284496736f + t * (1.421413741f +
               t * (-1.453152027f + t * 1.061405429f))));
  float erfax = 1.f - poly * __expf(-x * x);
  float erfx = copysignf(erfax, x);
  return 0.5f * v * (1.f + erfx);
}

__device__ __forceinline__ void gload_lds16(const void* g, void* l) {
  __builtin_amdgcn_global_load_lds(
      (const __attribute__((address_space(1))) unsigned int*)g,
      (__attribute__((address_space(3))) unsigned int*)l, 16, 0, 0);
}

// ---- merged transpose+cvt: w1[1024][16384] and w2[16384][1024] -> bf16^T ----
// 64x64 tiles; float4 reads (256B per 16-lane row), ushort4 writes (128B/16 ln)
__global__ void tcvt64_kernel(const float* __restrict__ w1, unsigned short* __restrict__ w1t,
                              const float* __restrict__ w2, unsigned short* __restrict__ w2t) {
  __shared__ float tile[64][68];
  int id = blockIdx.x;
  const float* src; unsigned short* dst; int R, C, bx, by;
  if (id < 4096) { src = w1; dst = w1t; R = 1024; C = 16384; bx = id & 255; by = id >> 8; }
  else { id -= 4096; src = w2; dst = w2t; R = 16384; C = 1024; bx = id & 15; by = id >> 4; }
  const int c0 = bx * 64, r0 = by * 64;
  const int t = threadIdx.x;
  #pragma unroll
  for (int i = 0; i < 4; ++i) {
    int idx = i * 256 + t;
    int row = idx >> 4, c4 = (idx & 15) * 4;
    float4 v = *(const float4*)&src[(size_t)(r0 + row) * C + c0 + c4];
    tile[row][c4] = v.x; tile[row][c4 + 1] = v.y;
    tile[row][c4 + 2] = v.z; tile[row][c4 + 3] = v.w;
  }
  __syncthreads();
  #pragma unroll
  for (int i = 0; i < 4; ++i) {
    int idx = i * 256 + t;
    int cOut = idx >> 4, r4 = (idx & 15) * 4;
    ushort4 o;
    o.x = f2b(tile[r4][cOut]);     o.y = f2b(tile[r4 + 1][cOut]);
    o.z = f2b(tile[r4 + 2][cOut]); o.w = f2b(tile[r4 + 3][cOut]);
    *(ushort4*)&dst[(size_t)(c0 + cOut) * R + r0 + r4] = o;
  }
}

// ---------------- router: logits, top-2, renorm; fused x->bf16; no hot atomics
__global__ void router_kernel(const float* __restrict__ x, const float* __restrict__ rw,
                              int* __restrict__ sel, float* __restrict__ selw,
                              unsigned short* __restrict__ xb) {
  int tok = (blockIdx.x * blockDim.x + threadIdx.x) >> 6;  // one wave per token
  int lane = threadIdx.x & 63;
  if (tok >= T_TOK) return;
  const float4* xr = (const float4*)(x + (size_t)tok * D_DIM);
  ushort4* xbr = (ushort4*)(xb + (size_t)tok * D_DIM);
  float acc[E_NUM];
  #pragma unroll
  for (int e = 0; e < E_NUM; ++e) acc[e] = 0.f;
  #pragma unroll
  for (int it = 0; it < 4; ++it) {
    int i = it * 64 + lane;      // float4 index, 0..255
    float4 v = xr[i];
    ushort4 o;
    o.x = f2b(v.x); o.y = f2b(v.y); o.z = f2b(v.z); o.w = f2b(v.w);
    xbr[i] = o;                  // fused bf16 conversion of x
    const float* w = rw + (size_t)i * 4 * E_NUM;
    #pragma unroll
    for (int e = 0; e < E_NUM; ++e) acc[e] += v.x * w[e];
    #pragma unroll
    for (int e = 0; e < E_NUM; ++e) acc[e] += v.y * w[E_NUM + e];
    #pragma unroll
    for (int e = 0; e < E_NUM; ++e) acc[e] += v.z * w[2 * E_NUM + e];
    #pragma unroll
    for (int e = 0; e < E_NUM; ++e) acc[e] += v.w * w[3 * E_NUM + e];
  }
  #pragma unroll
  for (int e = 0; e < E_NUM; ++e) {
    float v = acc[e];
    #pragma unroll
    for (int off = 32; off > 0; off >>= 1) v += __shfl_xor(v, off, 64);
    acc[e] = v;
  }
  if (lane == 0) {
    float mx = acc[0];
    #pragma unroll
    for (int e = 1; e < E_NUM; ++e) mx = fmaxf(mx, acc[e]);
    float p[E_NUM];
    #pragma unroll
    for (int e = 0; e < E_NUM; ++e) p[e] = __expf(acc[e] - mx);
    int i0 = 0;
    #pragma unroll
    for (int e = 1; e < E_NUM; ++e) if (p[e] > p[i0]) i0 = e;
    int i1 = (i0 == 0) ? 1 : 0;
    #pragma unroll
    for (int e = 0; e < E_NUM; ++e) if (e != i0 && p[e] > p[i1]) i1 = e;
    float w0 = p[i0], w1 = p[i1];
    float inv = 1.f / (w0 + w1);   // softmax denominator cancels in renorm
    sel[tok * 2] = i0; selw[tok * 2] = w0 * inv;
    sel[tok * 2 + 1] = i1; selw[tok * 2 + 1] = w1 * inv;
  }
}

// ---------------- counts: LDS-aggregated histogram ----------------
__global__ void count_kernel(const int* __restrict__ sel, int* __restrict__ counts) {
  __shared__ int lc[E_NUM];
  if (threadIdx.x < E_NUM) lc[threadIdx.x] = 0;
  __syncthreads();
  int t = blockIdx.x * blockDim.x + threadIdx.x;
  if (t < 2 * T_TOK) atomicAdd(&lc[sel[t]], 1);
  __syncthreads();
  if (threadIdx.x < E_NUM) atomicAdd(&counts[threadIdx.x], lc[threadIdx.x]);
}

// ---------------- plan: padded offsets + tile table + inits ----------------
__global__ void plan_kernel(const int* __restrict__ counts, int* __restrict__ tiles_e,
                            int* __restrict__ tiles_b, int* __restrict__ pad_off,
                            int* __restrict__ cursor, int* __restrict__ ptok,
                            float* __restrict__ pgate, unsigned short* __restrict__ zpad) {
  if (threadIdx.x == 0) {
    int b = 0, t = 0;
    for (int e = 0; e < E_NUM; ++e) {
      pad_off[e] = b;
      int nt = (counts[e] + BM - 1) >> 7;
      for (int i = 0; i < nt; ++i) { tiles_e[t] = e; tiles_b[t] = b + i * BM; ++t; }
      b += nt * BM;
    }
    for (; t < MAX_TILES; ++t) { tiles_e[t] = -1; tiles_b[t] = 0; }
  }
  for (int i = threadIdx.x; i < MAX_PAIRS_PAD; i += blockDim.x) { ptok[i] = -1; pgate[i] = 0.f; }
  for (int i = threadIdx.x; i < 64; i += blockDim.x) zpad[i] = 0;
  if (threadIdx.x < E_NUM) cursor[threadIdx.x] = 0;
}

// ---------------- scatter: block-level range reservation ----------------
__global__ void scatter_kernel(const int* __restrict__ sel, const float* __restrict__ selw,
                               const int* __restrict__ pad_off, int* __restrict__ cursor,
                               int* __restrict__ ptok, float* __restrict__ pgate) {
  __shared__ int lc[E_NUM];
  __shared__ int lbase[E_NUM];
  if (threadIdx.x < E_NUM) lc[threadIdx.x] = 0;
  __syncthreads();
  int t = blockIdx.x * blockDim.x + threadIdx.x;  // one thread per token
  int e0 = sel[t * 2], e1 = sel[t * 2 + 1];
  int o0 = atomicAdd(&lc[e0], 1);
  int o1 = atomicAdd(&lc[e1], 1);
  __syncthreads();
  if (threadIdx.x < E_NUM) lbase[threadIdx.x] = atomicAdd(&cursor[threadIdx.x], lc[threadIdx.x]);
  __syncthreads();
  int s0 = pad_off[e0] + lbase[e0] + o0;
  ptok[s0] = t; pgate[s0] = selw[t * 2];
  int s1 = pad_off[e1] + lbase[e1] + o1;
  ptok[s1] = t; pgate[s1] = selw[t * 2 + 1];
}

// ======== GEMM1: single-buffer BK=64 + T1 XCD chunking + T2 swizzle ========
__global__ __launch_bounds__(256, 3) void gemm1_kernel(
    const unsigned short* __restrict__ xb, const unsigned short* __restrict__ w1t,
    const int* __restrict__ ptok, const int* __restrict__ tiles_e,
    const int* __restrict__ tiles_b, const unsigned short* __restrict__ zpad,
    unsigned short* __restrict__ h) {
  const int id = blockIdx.x + 16 * blockIdx.y;
  const int xcd = id & 7;
  const int j = id >> 3;                     // 0..271 per XCD
  const int tileIdx = xcd * 17 + (j >> 4);   // 17 tiles per XCD
  const int n0 = (j & 15) * 128;
  const int e = tiles_e[tileIdx];
  if (e < 0) return;
  const int base = tiles_b[tileIdx];

  __shared__ unsigned short As[BM * BK];
  __shared__ unsigned short Bs[BM * BK];

  const int tid = threadIdx.x;
  const int lane = tid & 63;
  const int wv = tid >> 6;
  const int wr = wv >> 1, wc = wv & 1;
  const int lr = lane & 15;
  const int lq = lane >> 4;
  const int lsw = lr & 7;                     // read-side swizzle key

  int atok[4], aoff[4];
  const unsigned short* bptr[4];
  #pragma unroll
  for (int i = 0; i < 4; ++i) {
    int c = i * 256 + tid;
    int row = c >> 3, kc = c & 7;
    int kcs = kc ^ (row & 7);                 // inverse-swizzled source chunk
    atok[i] = ptok[base + row];
    aoff[i] = kcs * 8;
    bptr[i] = w1t + (size_t)(e * DFF_DIM + n0 + row) * D_DIM + kcs * 8;
  }

  f32x4 acc[4][4];
  #pragma unroll
  for (int m = 0; m < 4; ++m)
    #pragma unroll
    for (int n = 0; n < 4; ++n) acc[m][n] = (f32x4){0.f, 0.f, 0.f, 0.f};

  for (int k0 = 0; k0 < D_DIM; k0 += BK) {
    #pragma unroll
    for (int i = 0; i < 4; ++i) {
      const unsigned short* ga =
          (atok[i] >= 0) ? (xb + (size_t)atok[i] * D_DIM + k0 + aoff[i]) : zpad;
      gload_lds16(ga, &As[(i * 256 + tid) * 8]);          // LDS dest linear
      gload_lds16(bptr[i] + k0, &Bs[(i * 256 + tid) * 8]);
    }
    __syncthreads();
    #pragma unroll
    for (int kk = 0; kk < BK; kk += 32) {
      const int ch = (((kk >> 5) * 4 + lq) ^ lsw) * 8;    // swizzled read chunk
      short8_t aF[4], bF[4];
      #pragma unroll
      for (int m = 0; m < 4; ++m)
        aF[m] = *(const short8_t*)&As[(wr * 64 + m * 16 + lr) * BK + ch];
      #pragma unroll
      for (int n = 0; n < 4; ++n)
        bF[n] = *(const short8_t*)&Bs[(wc * 64 + n * 16 + lr) * BK + ch];
      #pragma unroll
      for (int m = 0; m < 4; ++m)
        #pragma unroll
        for (int n = 0; n < 4; ++n)
          acc[m][n] = __builtin_amdgcn_mfma_f32_16x16x32_bf16(aF[m], bF[n], acc[m][n], 0, 0, 0);
    }
    __syncthreads();
  }

  #pragma unroll
  for (int m = 0; m < 4; ++m) {
    #pragma unroll
    for (int n = 0; n < 4; ++n) {
      const int col = n0 + wc * 64 + n * 16 + lr;
      #pragma unroll
      for (int j4 = 0; j4 < 4; ++j4) {
        const int row = base + wr * 64 + m * 16 + lq * 4 + j4;
        h[(size_t)row * DFF_DIM + col] = f2b(fast_gelu(acc[m][n][j4]));
      }
    }
  }
}

// ======== GEMM2: single-buffer BK=64 + T1 XCD chunking + T2 swizzle ========
// out[tok] += gate * (h @ W2_e)
__global__ __launch_bounds__(256, 3) void gemm2_kernel(
    const unsigned short* __restrict__ h, const unsigned short* __restrict__ w2t,
    const int* __restrict__ ptok, const float* __restrict__ pgate,
    const int* __restrict__ tiles_e, const int* __restrict__ tiles_b,
    float* __restrict__ out) {
  const int id = blockIdx.x + 8 * blockIdx.y;
  const int xcd = id & 7;
  const int j = id >> 3;                     // 0..135 per XCD
  const int tileIdx = xcd * 17 + (j >> 3);   // 17 tiles per XCD
  const int n0 = (j & 7) * 128;
  const int e = tiles_e[tileIdx];
  if (e < 0) return;
  const int base = tiles_b[tileIdx];

  __shared__ unsigned short As[BM * BK];
  __shared__ unsigned short Bs[BM * BK];

  const int tid = threadIdx.x;
  const int lane = tid & 63;
  const int wv = tid >> 6;
  const int wr = wv >> 1, wc = wv & 1;
  const int lr = lane & 15;
  const int lq = lane >> 4;
  const int lsw = lr & 7;

  const unsigned short* aptr[4];
  const unsigned short* bptr[4];
  #pragma unroll
  for (int i = 0; i < 4; ++i) {
    int c = i * 256 + tid;
    int row = c >> 3, kc = c & 7;
    int kcs = kc ^ (row & 7);                 // inverse-swizzled source chunk
    aptr[i] = h + (size_t)(base + row) * DFF_DIM + kcs * 8;
    bptr[i] = w2t + (size_t)(n0 + row) * (E_NUM * DFF_DIM) + e * DFF_DIM + kcs * 8;
  }

  f32x4 acc[4][4];
  #pragma unroll
  for (int m = 0; m < 4; ++m)
    #pragma unroll
    for (int n = 0; n < 4; ++n) acc[m][n] = (f32x4){0.f, 0.f, 0.f, 0.f};

  for (int k0 = 0; k0 < DFF_DIM; k0 += BK) {
    #pragma unroll
    for (int i = 0; i < 4; ++i) {
      gload_lds16(aptr[i] + k0, &As[(i * 256 + tid) * 8]);
      gload_lds16(bptr[i] + k0, &Bs[(i * 256 + tid) * 8]);
    }
    __syncthreads();
    #pragma unroll
    for (int kk = 0; kk < BK; kk += 32) {
      const int ch = (((kk >> 5) * 4 + lq) ^ lsw) * 8;
      short8_t aF[4], bF[4];
      #pragma unroll
      for (int m = 0; m < 4; ++m)
        aF[m] = *(const short8_t*)&As[(wr * 64 + m * 16 + lr) * BK + ch];
      #pragma unroll
      for (int n = 0; n < 4; ++n)
        bF[n] = *(const short8_t*)&Bs[(wc * 64 + n * 16 + lr) * BK + ch];
      #pragma unroll
      for (int m = 0; m < 4; ++m)
        #pragma unroll
        for (int n = 0; n < 4; ++n)
          acc[m][n] = __builtin_amdgcn_mfma_f32_16x16x32_bf16(aF[m], bF[n], acc[m][n], 0, 0, 0);
    }
    __syncthreads();
  }

  #pragma unroll
  for (int m = 0; m < 4; ++m) {
    #pragma unroll
    for (int j4 = 0; j4 < 4; ++j4) {
      const int p = base + wr * 64 + m * 16 + lq * 4 + j4;
      const int tok = ptok[p];
      if (tok < 0) continue;
      const float g = pgate[p];
      #pragma unroll
      for (int n = 0; n < 4; ++n) {
        const int col = n0 + wc * 64 + n * 16 + lr;
        atomicAdd(&out[(size_t)tok * D_DIM + col], g * acc[m][n][j4]);
      }
    }
  }
}

// ---------------- launch ----------------
extern "C" void kernel_launch(void* const* d_in, const int* in_sizes, int n_in,
                              void* d_out, int out_size, void* d_ws, size_t ws_size,
                              hipStream_t stream) {
  const float* x  = (const float*)d_in[0];
  const float* rw = (const float*)d_in[1];
  const float* w1 = (const float*)d_in[2];
  const float* w2 = (const float*)d_in[3];
  float* out = (float*)d_out;

  char* ws = (char*)d_ws;
  unsigned short* xb   = (unsigned short*)(ws);              // 16,777,216
  unsigned short* w1t  = (unsigned short*)(ws + 16777216);   // 33,554,432  [16384][1024]
  unsigned short* w2t  = (unsigned short*)(ws + 50331648);   // 33,554,432  [1024][16384]
  unsigned short* h    = (unsigned short*)(ws + 83886080);   // 71,303,168  [17408][2048]
  int*   ptok   = (int*)(ws + 155189248);
  float* pgate  = (float*)(ws + 155258880);
  int*   sel    = (int*)(ws + 155328512);
  float* selw   = (float*)(ws + 155394048);
  int*   counts = (int*)(ws + 155459584);
  int*   cursor = counts + 8;
  int*   padoff = counts + 16;
  int*   tiles_e = counts + 24;
  int*   tiles_b = tiles_e + MAX_TILES;
  unsigned short* zpad = (unsigned short*)(tiles_b + MAX_TILES);
  const size_t WS_NEED = 155459584 + 4096;
  if (ws_size < WS_NEED) return;

  hipMemsetAsync(out, 0, (size_t)T_TOK * D_DIM * sizeof(float), stream);
  hipMemsetAsync(counts, 0, E_NUM * sizeof(int), stream);

  tcvt64_kernel<<<8192, 256, 0, stream>>>(w1, w1t, w2, w2t);
  router_kernel<<<T_TOK / 4, 256, 0, stream>>>(x, rw, sel, selw, xb);
  count_kernel<<<2 * T_TOK / 256, 256, 0, stream>>>(sel, counts);
  plan_kernel<<<1, 256, 0, stream>>>(counts, tiles_e, tiles_b, padoff, cursor, ptok, pgate, zpad);
  scatter_kernel<<<T_TOK / 256, 256, 0, stream>>>(sel, selw, padoff, cursor, ptok, pgate);
  gemm1_kernel<<<dim3(DFF_DIM / 128, MAX_TILES), 256, 0, stream>>>(xb, w1t, ptok, tiles_e,
                                                                   tiles_b, zpad, h);
  gemm2_kernel<<<dim3(D_DIM / 128, MAX_TILES), 256, 0, stream>>>(h, w2t, ptok, pgate, tiles_e,
                                                                 tiles_b, out);
}